// Round 1
// baseline (236.169 us; speedup 1.0000x reference)
//
#include <hip/hip_runtime.h>

#define S_LEN 2048
#define DMODEL 1024
#define NBATCH 4

typedef unsigned short u16;
typedef __bf16 bf16x8 __attribute__((ext_vector_type(8)));
typedef float f32x4 __attribute__((ext_vector_type(4)));

__device__ __forceinline__ u16 f2bf(float f) {
  union { float f; unsigned u; } v;
  v.f = f;
  unsigned r = v.u + 0x7fffu + ((v.u >> 16) & 1u);
  return (u16)(r >> 16);
}

// ---------------- convert x: fp32 -> bf16, flat ----------------
__global__ void convert_x_kernel(const float* __restrict__ x, u16* __restrict__ xb, long n) {
  long i = ((long)blockIdx.x * blockDim.x + threadIdx.x) * 4;
  long stride = (long)gridDim.x * blockDim.x * 4;
  for (; i < n; i += stride) {
    float4 v = *reinterpret_cast<const float4*>(x + i);
    ushort4 o;
    o.x = f2bf(v.x); o.y = f2bf(v.y); o.z = f2bf(v.z); o.w = f2bf(v.w);
    *reinterpret_cast<ushort4*>(xb + i) = o;
  }
}

// ---------------- transpose-convert W: Wt[n][k] = bf16(W[k][n]), 1024x1024 ----------------
__global__ void transpose_w_kernel(const float* __restrict__ W, u16* __restrict__ Wt) {
  __shared__ float tile[32][33];
  int tx = threadIdx.x, ty = threadIdx.y;
  int k0 = blockIdx.x * 32, n0 = blockIdx.y * 32;
#pragma unroll
  for (int i = 0; i < 32; i += 8)
    tile[ty + i][tx] = W[(long)(k0 + ty + i) * DMODEL + n0 + tx];
  __syncthreads();
#pragma unroll
  for (int i = 0; i < 32; i += 8)
    Wt[(long)(n0 + ty + i) * DMODEL + k0 + tx] = f2bf(tile[tx][ty + i]);
}

// ---------------- NT GEMM: C[M][N] = A[M][K] * B[N][K]^T ----------------
// 128x128 tile, BK=32, 256 threads (4 waves in 2x2, each 64x64 via 4x4 16x16x32 MFMA frags)
// CMODE: 0 = f32 C row-major; 1 = bf16 C row-major; 2 = bf16 transposed write Vt[b][col][s]
// CAUSAL: 0 = none; 1 = skip blocks bn>bm (scores); 2 = K-limit (bm+1)*128 (PV)
template<int CMODE, int CAUSAL>
__global__ __launch_bounds__(256) void gemm_nt(
    const u16* __restrict__ A, const u16* __restrict__ B, void* __restrict__ Cptr,
    int lda, int ldb, int ldc, int Kdim,
    long sAz, long sBz, long sCz)
{
  int bm = blockIdx.x, bn = blockIdx.y, bz = blockIdx.z;
  if (CAUSAL == 1 && bn > bm) return;
  const u16* Ab = A + (long)bz * sAz + (long)(bm * 128) * lda;
  const u16* Bb = B + (long)bz * sBz + (long)(bn * 128) * ldb;
  int Keff = Kdim;
  if (CAUSAL == 2) { int lim = (bm + 1) * 128; if (lim < Keff) Keff = lim; }

  __shared__ u16 atile[128 * 32];
  __shared__ u16 btile[128 * 32];

  int tid = threadIdx.x;
  int lane = tid & 63, wave = tid >> 6;
  int wr = wave >> 1, wc = wave & 1;
  int l15 = lane & 15, lhi = lane >> 4;

  f32x4 zero = {0.f, 0.f, 0.f, 0.f};
  f32x4 acc[4][4];
#pragma unroll
  for (int m = 0; m < 4; ++m)
#pragma unroll
    for (int n = 0; n < 4; ++n) acc[m][n] = zero;

  int r0 = tid >> 2;         // 0..63 : staged row within 64-row chunk
  int c0 = (tid & 3) * 8;    // 0,8,16,24 : bf16 col offset (16B granules)

  for (int k0 = 0; k0 < Keff; k0 += 32) {
    uint4 a0 = *reinterpret_cast<const uint4*>(Ab + (long)r0 * lda + k0 + c0);
    uint4 a1 = *reinterpret_cast<const uint4*>(Ab + (long)(r0 + 64) * lda + k0 + c0);
    uint4 b0 = *reinterpret_cast<const uint4*>(Bb + (long)r0 * ldb + k0 + c0);
    uint4 b1 = *reinterpret_cast<const uint4*>(Bb + (long)(r0 + 64) * ldb + k0 + c0);
    __syncthreads();
    *reinterpret_cast<uint4*>(atile + r0 * 32 + c0) = a0;
    *reinterpret_cast<uint4*>(atile + (r0 + 64) * 32 + c0) = a1;
    *reinterpret_cast<uint4*>(btile + r0 * 32 + c0) = b0;
    *reinterpret_cast<uint4*>(btile + (r0 + 64) * 32 + c0) = b1;
    __syncthreads();

    bf16x8 af[4], bfr[4];
#pragma unroll
    for (int m = 0; m < 4; ++m)
      af[m] = *reinterpret_cast<const bf16x8*>(atile + (wr * 64 + m * 16 + l15) * 32 + lhi * 8);
#pragma unroll
    for (int n = 0; n < 4; ++n)
      bfr[n] = *reinterpret_cast<const bf16x8*>(btile + (wc * 64 + n * 16 + l15) * 32 + lhi * 8);
#pragma unroll
    for (int m = 0; m < 4; ++m)
#pragma unroll
      for (int n = 0; n < 4; ++n)
        acc[m][n] = __builtin_amdgcn_mfma_f32_16x16x32_bf16(af[m], bfr[n], acc[m][n], 0, 0, 0);
  }

  int rowBase = bm * 128 + wr * 64;
  int colBase = bn * 128 + wc * 64;

  if constexpr (CMODE == 0) {
    float* C = (float*)Cptr + (long)bz * sCz;
#pragma unroll
    for (int m = 0; m < 4; ++m) {
      int rr = rowBase + m * 16 + lhi * 4;
#pragma unroll
      for (int n = 0; n < 4; ++n) {
        int col = colBase + n * 16 + l15;
#pragma unroll
        for (int r = 0; r < 4; ++r)
          C[(long)(rr + r) * ldc + col] = acc[m][n][r];
      }
    }
  } else if constexpr (CMODE == 1) {
    u16* C = (u16*)Cptr + (long)bz * sCz;
#pragma unroll
    for (int m = 0; m < 4; ++m) {
      int rr = rowBase + m * 16 + lhi * 4;
#pragma unroll
      for (int n = 0; n < 4; ++n) {
        int col = colBase + n * 16 + l15;
#pragma unroll
        for (int r = 0; r < 4; ++r)
          C[(long)(rr + r) * ldc + col] = f2bf(acc[m][n][r]);
      }
    }
  } else {
    // transposed V write: value at (row=s-global, col=e) -> Vt[b][e][s], 4 consecutive s per lane
    u16* C = (u16*)Cptr;
#pragma unroll
    for (int m = 0; m < 4; ++m) {
      int rr = rowBase + m * 16 + lhi * 4;
      int b = rr >> 11, s = rr & 2047;
#pragma unroll
      for (int n = 0; n < 4; ++n) {
        int col = colBase + n * 16 + l15;
        ushort4 v;
        v.x = f2bf(acc[m][n][0]); v.y = f2bf(acc[m][n][1]);
        v.z = f2bf(acc[m][n][2]); v.w = f2bf(acc[m][n][3]);
        *reinterpret_cast<ushort4*>(C + (long)b * (DMODEL * (long)S_LEN) + (long)col * S_LEN + s) = v;
      }
    }
  }
}

// ---------------- causal row softmax: scores(f32, unscaled) -> P(bf16, normalized) ----------------
__global__ __launch_bounds__(256) void softmax_row_kernel(const float* __restrict__ scores,
                                                          u16* __restrict__ P) {
  int q = blockIdx.x, b = blockIdx.y;
  const float* srow = scores + ((long)b * S_LEN + q) * S_LEN;
  u16* prow = P + ((long)b * S_LEN + q) * S_LEN;
  int n = q + 1;
  int tid = threadIdx.x;
  const float scale = 0.03125f; // 1/sqrt(1024)

  __shared__ float red[8];

  // pass 1: max
  float m = -1e30f;
  for (int j = tid; j < n; j += 256) m = fmaxf(m, srow[j]);
#pragma unroll
  for (int off = 32; off > 0; off >>= 1) m = fmaxf(m, __shfl_down(m, off, 64));
  if ((tid & 63) == 0) red[tid >> 6] = m;
  __syncthreads();
  if (tid == 0) red[4] = fmaxf(fmaxf(red[0], red[1]), fmaxf(red[2], red[3]));
  __syncthreads();
  float ms = red[4] * scale;

  // pass 2: sum of exp
  float s = 0.f;
  for (int j = tid; j < n; j += 256) s += __expf(srow[j] * scale - ms);
#pragma unroll
  for (int off = 32; off > 0; off >>= 1) s += __shfl_down(s, off, 64);
  if ((tid & 63) == 0) red[tid >> 6] = s;
  __syncthreads();
  if (tid == 0) red[5] = red[0] + red[1] + red[2] + red[3];
  __syncthreads();
  float inv = 1.f / red[5];

  // pass 3: write P (zeros above diagonal)
  for (int j = tid; j < n; j += 256)
    prow[j] = f2bf(__expf(srow[j] * scale - ms) * inv);
  for (int j = n + tid; j < S_LEN; j += 256)
    prow[j] = 0;
}

// ---------------- launch ----------------
extern "C" void kernel_launch(void* const* d_in, const int* in_sizes, int n_in,
                              void* d_out, int out_size, void* d_ws, size_t ws_size,
                              hipStream_t stream) {
  const float* x  = (const float*)d_in[0];
  const float* Wq = (const float*)d_in[1];
  const float* Wk = (const float*)d_in[2];
  const float* Wv = (const float*)d_in[3];
  float* out = (float*)d_out;

  // workspace layout (bytes)
  char* ws = (char*)d_ws;
  u16*   xb  = (u16*)(ws);                    // 8192x1024 bf16         : 16,777,216
  u16*   wtb = (u16*)(ws + 16777216);         // 3 x 1024x1024 bf16 (W^T): 6,291,456
  u16*   Qb  = (u16*)(ws + 23068672);         // [4][2048][1024] bf16   : 16,777,216
  u16*   Kb  = (u16*)(ws + 39845888);         // [4][2048][1024] bf16   : 16,777,216
  u16*   Vtb = (u16*)(ws + 56623104);         // [4][1024][2048] bf16   : 16,777,216
  float* sc  = (float*)(ws + 73400320);       // [4][2048][2048] f32    : 67,108,864
  u16*   P   = (u16*)(ws + 140509184);        // [4][2048][2048] bf16   : 33,554,432
  // total: 174,063,616 bytes

  long nx = (long)NBATCH * S_LEN * DMODEL;
  convert_x_kernel<<<2048, 256, 0, stream>>>(x, xb, nx);

  dim3 tb(32, 8);
  transpose_w_kernel<<<dim3(32, 32), tb, 0, stream>>>(Wq, wtb);
  transpose_w_kernel<<<dim3(32, 32), tb, 0, stream>>>(Wk, wtb + 1024 * 1024);
  transpose_w_kernel<<<dim3(32, 32), tb, 0, stream>>>(Wv, wtb + 2 * 1024 * 1024);

  // projections: M=8192 (B*S), N=1024, K=1024.  Q,K row-major bf16; V written transposed.
  gemm_nt<1, 0><<<dim3(64, 8, 1), 256, 0, stream>>>(xb, wtb,               Qb,  DMODEL, DMODEL, DMODEL, DMODEL, 0, 0, 0);
  gemm_nt<1, 0><<<dim3(64, 8, 1), 256, 0, stream>>>(xb, wtb + 1024 * 1024, Kb,  DMODEL, DMODEL, DMODEL, DMODEL, 0, 0, 0);
  gemm_nt<2, 0><<<dim3(64, 8, 1), 256, 0, stream>>>(xb, wtb + 2 * 1024 * 1024, Vtb, DMODEL, DMODEL, S_LEN, DMODEL, 0, 0, 0);

  // scores (unscaled): per batch, S = Q * K^T, causal tile skip, f32 out
  gemm_nt<0, 1><<<dim3(16, 16, 4), 256, 0, stream>>>(Qb, Kb, sc, DMODEL, DMODEL, S_LEN, DMODEL,
                                                     (long)S_LEN * DMODEL, (long)S_LEN * DMODEL,
                                                     (long)S_LEN * S_LEN);

  // softmax rows (applies 1/sqrt(dk) scale, causal mask, writes bf16 P with zeros)
  softmax_row_kernel<<<dim3(S_LEN, NBATCH), 256, 0, stream>>>(sc, P);

  // O = P * V : A = P [2048][2048] bf16, B = Vt [1024][2048] bf16, C = out f32, causal K-limit
  gemm_nt<0, 2><<<dim3(16, 8, 4), 256, 0, stream>>>(P, Vtb, out, S_LEN, S_LEN, DMODEL, S_LEN,
                                                    (long)S_LEN * S_LEN, (long)DMODEL * S_LEN,
                                                    (long)S_LEN * DMODEL);
}